// Round 7
// baseline (198.335 us; speedup 1.0000x reference)
//
#include <hip/hip_runtime.h>

#define Bb 4
#define Nn 2048
#define Dd 1024
#define Rr 64
#define LN_EPS 1e-5f

typedef unsigned short u16;
typedef short bf16x8 __attribute__((ext_vector_type(8)));   // 8 bf16 in 4 VGPRs
typedef float f32x4 __attribute__((ext_vector_type(4)));

__device__ __forceinline__ u16 f2bf(float f) {
  unsigned u = __float_as_uint(f);
  u += 0x7FFFu + ((u >> 16) & 1u);   // RNE
  return (u16)(u >> 16);
}

// async global->LDS, 16 B per lane. LDS dest is wave-uniform base + lane*16.
__device__ __forceinline__ void g2l16(u16* l, const u16* g) {
  __builtin_amdgcn_global_load_lds(
      (const __attribute__((address_space(1))) unsigned int*)g,
      (__attribute__((address_space(3))) unsigned int*)l, 16, 0, 0);
}

// ---- prep_fused: blocks 0..2047 = prep_x transpose; 2048..2079 = U/V
// transpose; 2080..4127 = qscale. R7: merged (one launch saved).
__global__ __launch_bounds__(256) void prep_fused(const float* __restrict__ x,
    u16* __restrict__ xt, const float* __restrict__ U,
    const float* __restrict__ V, const float* __restrict__ mask,
    u16* __restrict__ uvt, float* __restrict__ qs) {
  __shared__ float tile[64][65];
  const int bid = blockIdx.x;
  const int t = threadIdx.x;
  if (bid < 2048) {
    const int b = bid >> 9;
    const int d0 = ((bid >> 5) & 15) * 64;
    const int n0 = (bid & 31) * 64;
    const int c = t & 63, r4 = t >> 6;
#pragma unroll
    for (int rr = 0; rr < 16; rr++) {
      int row = rr * 4 + r4;
      tile[row][c] = x[(size_t)(b * Nn + n0 + row) * Dd + d0 + c];
    }
    __syncthreads();
    const int c2 = t & 31, r8 = t >> 5;
#pragma unroll
    for (int rr = 0; rr < 8; rr++) {
      int dd = rr * 8 + r8;
      unsigned lo = f2bf(tile[2 * c2][dd]);
      unsigned hi = f2bf(tile[2 * c2 + 1][dd]);
      *(unsigned*)&xt[(size_t)(b * Dd + d0 + dd) * Nn + n0 + 2 * c2] = lo | (hi << 16);
    }
  } else if (bid < 2080) {
    const int sub = bid - 2048;
    const int which = sub >> 4;
    const int d0 = (sub & 15) * 64;
    const float* src = which ? V : U;
    const int c = t & 63, r4 = t >> 6;
#pragma unroll
    for (int rr = 0; rr < 16; rr++) {
      int row = rr * 4 + r4;
      tile[row][c] = src[(size_t)(d0 + row) * Rr + c];
    }
    __syncthreads();
#pragma unroll
    for (int rr = 0; rr < 16; rr++) {
      int r = rr * 4 + r4;
      uvt[(size_t)(which * 64 + r) * Dd + d0 + c] = f2bf(tile[c][r]);
    }
  } else {
    const int row = (bid - 2080) * 4 + (t >> 6);
    const int lane = t & 63;
    float v = mask[(size_t)row * Rr + lane];
#pragma unroll
    for (int off = 32; off; off >>= 1) v += __shfl_xor(v, off);
    if (lane == 0) qs[row] = rsqrtf(fmaxf(v, 1.0f));
  }
}

// ---- proj_qk: Q = (x@U)*mask, K = (x@V)*mask, bf16 out.
// R7: 16 rows x 128 cols/block, grid 512 (was 32 rows/grid 256 = 1 block/CU
// = 1 wave/SIMD -> zero latency hiding). Now 2 blocks/CU, 2 waves/SIMD, and
// per-wave f32->bf16 convert VALU halves. Same traffic, same math.
__global__ __launch_bounds__(256) void proj_qk(const float* __restrict__ x,
    const float* __restrict__ mask, const u16* __restrict__ uvt,
    u16* __restrict__ Qo, u16* __restrict__ Ko) {
  const int t = threadIdx.x;
  const int w = t >> 6, l = t & 63, quad = l >> 4, l16 = l & 15;
  const int g0 = blockIdx.x * 16;
  f32x4 acc[2];
#pragma unroll
  for (int i = 0; i < 2; i++) acc[i] = (f32x4){0.f, 0.f, 0.f, 0.f};
  for (int k0 = 0; k0 < Dd; k0 += 32) {
    const float4* px = (const float4*)&x[(size_t)(g0 + l16) * Dd + k0 + quad * 8];
    float4 x0 = px[0], x1 = px[1];
    bf16x8 av;
    av[0] = (short)f2bf(x0.x); av[1] = (short)f2bf(x0.y);
    av[2] = (short)f2bf(x0.z); av[3] = (short)f2bf(x0.w);
    av[4] = (short)f2bf(x1.x); av[5] = (short)f2bf(x1.y);
    av[6] = (short)f2bf(x1.z); av[7] = (short)f2bf(x1.w);
    bf16x8 bfr[2];
#pragma unroll
    for (int i = 0; i < 2; i++) {
      int col = (w * 2 + i) * 16 + l16;
      bfr[i] = *(const bf16x8*)&uvt[(size_t)col * Dd + k0 + quad * 8];
    }
#pragma unroll
    for (int i = 0; i < 2; i++)
      acc[i] = __builtin_amdgcn_mfma_f32_16x16x32_bf16(av, bfr[i], acc[i], 0, 0, 0);
  }
#pragma unroll
  for (int i = 0; i < 2; i++) {
    int col = (w * 2 + i) * 16 + l16;
    int r_ = col & 63;
#pragma unroll
    for (int r = 0; r < 4; r++) {
      int row = g0 + quad * 4 + r;
      float v = acc[i][r] * mask[(size_t)row * Rr + r_];
      u16 bv = f2bf(v);
      if (col < 64) Qo[(size_t)row * Rr + r_] = bv;
      else          Ko[(size_t)row * Rr + r_] = bv;
    }
  }
}

// ---- score_softmax: R7: block = 16 q-rows x ALL 2048 keys, 8 waves,
// grid 512 (was 32 rows/grid 256: 1 block/CU, acc=128 VGPR, 2 waves/SIMD).
// acc[16] halves register pressure -> 2 blocks/CU = 4 waves/SIMD; the
// serial max/sum cross-wave sections halve. Same traffic, same math.
__global__ __launch_bounds__(512, 2) void score_softmax(
    const u16* __restrict__ Qm, const u16* __restrict__ Km,
    const float* __restrict__ qs, u16* __restrict__ Pw,
    float* __restrict__ linv_g) {
  __shared__ float red[16][8];
  __shared__ float mfin[16];
  const int t = threadIdx.x;
  const int w = t >> 6, l = t & 63, quad = l >> 4, l16 = l & 15;
  const int id = blockIdx.x;
  const int xcd = id & 7;
  const int b = xcd >> 1;
  const int q0 = (((id >> 3) << 1) | (xcd & 1)) * 16;
  bf16x8 qf[2];
#pragma unroll
  for (int ks = 0; ks < 2; ks++)
    qf[ks] = *(const bf16x8*)&Qm[(size_t)(b * Nn + q0 + l16) * Rr + ks * 32 + quad * 8];
  f32x4 acc[16];
#pragma unroll
  for (int nt = 0; nt < 16; nt++) acc[nt] = (f32x4){0.f, 0.f, 0.f, 0.f};
#pragma unroll
  for (int nt = 0; nt < 16; nt++) {
#pragma unroll
    for (int ks = 0; ks < 2; ks++) {
      bf16x8 kf = *(const bf16x8*)&Km[(size_t)(b * Nn + w * 256 + nt * 16 + l16) * Rr + ks * 32 + quad * 8];
      acc[nt] = __builtin_amdgcn_mfma_f32_16x16x32_bf16(qf[ks], kf, acc[nt], 0, 0, 0);
    }
  }
  float sc[4];
#pragma unroll
  for (int r = 0; r < 4; r++)
    sc[r] = qs[(size_t)b * Nn + q0 + quad * 4 + r];
#pragma unroll
  for (int nt = 0; nt < 16; nt++)
#pragma unroll
    for (int r = 0; r < 4; r++) acc[nt][r] *= sc[r];
  float vmax[4];
#pragma unroll
  for (int r = 0; r < 4; r++) {
    float m = -1e30f;
#pragma unroll
    for (int nt = 0; nt < 16; nt++) m = fmaxf(m, acc[nt][r]);
#pragma unroll
    for (int off = 1; off < 16; off <<= 1) m = fmaxf(m, __shfl_xor(m, off));
    vmax[r] = m;
  }
  if (l16 == 0) {
#pragma unroll
    for (int r = 0; r < 4; r++) red[quad * 4 + r][w] = vmax[r];
  }
  __syncthreads();
  if (t < 16) {
    float m = -1e30f;
#pragma unroll
    for (int i = 0; i < 8; i++) m = fmaxf(m, red[t][i]);
    mfin[t] = m;
  }
  __syncthreads();
  float rowm[4], vsum[4];
#pragma unroll
  for (int r = 0; r < 4; r++) {
    rowm[r] = mfin[quad * 4 + r];
    vsum[r] = 0.f;
  }
#pragma unroll
  for (int nt = 0; nt < 16; nt++)
#pragma unroll
    for (int r = 0; r < 4; r++) {
      float p = __expf(acc[nt][r] - rowm[r]);
      acc[nt][r] = p;
      vsum[r] += p;
    }
#pragma unroll
  for (int r = 0; r < 4; r++) {
#pragma unroll
    for (int off = 1; off < 16; off <<= 1) vsum[r] += __shfl_xor(vsum[r], off);
  }
  __syncthreads();   // red[] reuse
  if (l16 == 0) {
#pragma unroll
    for (int r = 0; r < 4; r++) red[quad * 4 + r][w] = vsum[r];
  }
  __syncthreads();
  if (t < 16) {
    float s = 0.f;
#pragma unroll
    for (int i = 0; i < 8; i++) s += red[t][i];
    linv_g[(size_t)b * Nn + q0 + t] = 1.f / s;
  }
#pragma unroll
  for (int nt = 0; nt < 16; nt++) {
    const size_t base = ((size_t)(b * Nn + q0 + quad * 4)) * Nn + w * 256 + nt * 16 + l16;
#pragma unroll
    for (int r = 0; r < 4; r++)
      Pw[base + (size_t)r * Nn] = f2bf(acc[nt][r]);
  }
}

// ---- pv_gemm: delta = P @ X. 128x128 tile, BK=64, 512 thr (8 waves 2Mx4N),
// double-buffered LDS + counted vmcnt — R5 exact (best measured 44.2 us;
// R6's 4-wave variant was worse, LDS-pipe model refuted).
__global__ __launch_bounds__(512, 4) void pv_gemm(
    const u16* __restrict__ Pw, const u16* __restrict__ xt,
    const float* __restrict__ x, const float* __restrict__ linv_g,
    float* __restrict__ y) {
  __shared__ u16 As[2][128 * 64];   // [buf][row m][k-slot] swizzled, 16 KB ea
  __shared__ u16 Bs[2][128 * 64];   // [buf][col n(d)][k-slot] swizzled
  const int t = threadIdx.x;
  const int w = t >> 6, l = t & 63, quad = l >> 4, l16 = l & 15;
  const int id = blockIdx.x;
  const int xcd = id & 7;
  const int b = xcd >> 1;
  const int nh = xcd & 1;
  const int rest = id >> 3;             // 0..63
  const int m0 = (rest & 15) * 128;     // 16 m-tiles
  const int n0 = (nh * 4 + (rest >> 4)) * 128;  // 8 n-tiles
  const int lrow = l >> 3;              // 0..7
  const int srow = w * 8 + lrow;        // staging row 0..63 (+64 second round)
  const int skoff = ((l & 7) ^ lrow) * 8;  // swizzled global k-chunk
  const size_t gA = (size_t)(b * Nn + m0 + srow) * Nn + skoff;
  const size_t gB = (size_t)(b * Dd + n0 + srow) * Nn + skoff;
  const int wm = w >> 2, wn = w & 3;    // 2M x 4N wave grid
  const int sw = l16 & 7;
  f32x4 acc[4][2];
#pragma unroll
  for (int i = 0; i < 4; i++)
#pragma unroll
    for (int j = 0; j < 2; j++) acc[i][j] = (f32x4){0.f, 0.f, 0.f, 0.f};

#define STAGE(bf, k0)                                              \
  do {                                                             \
    g2l16(&As[bf][(w * 8) * 64],      &Pw[gA + (size_t)(k0)]);     \
    g2l16(&As[bf][(64 + w * 8) * 64], &Pw[gA + 64 * Nn + (size_t)(k0)]); \
    g2l16(&Bs[bf][(w * 8) * 64],      &xt[gB + (size_t)(k0)]);     \
    g2l16(&Bs[bf][(64 + w * 8) * 64], &xt[gB + 64 * Nn + (size_t)(k0)]); \
  } while (0)

  STAGE(0, 0);   // tile 0 in flight (4 outstanding/wave)
  for (int kt = 0; kt < Nn / 64; kt++) {
    const int cur = kt & 1;
    if (kt + 1 < Nn / 64) {
      STAGE(cur ^ 1, (kt + 1) * 64);              // up to 8 outstanding
      asm volatile("s_waitcnt vmcnt(4)" ::: "memory");  // tile kt done; kt+1 flies
    } else {
      asm volatile("s_waitcnt vmcnt(0)" ::: "memory");  // last tile: drain it
    }
    __builtin_amdgcn_s_barrier();                 // all waves' tile-kt data in LDS
    asm volatile("" ::: "memory");
#pragma unroll
    for (int ks = 0; ks < 2; ks++) {
      const int slot = ((ks * 4 + quad) ^ sw) * 8;
      bf16x8 af[4], bf_[2];
#pragma unroll
      for (int mt = 0; mt < 4; mt++)
        af[mt] = *(const bf16x8*)&As[cur][(wm * 64 + mt * 16 + l16) * 64 + slot];
#pragma unroll
      for (int nt = 0; nt < 2; nt++)
        bf_[nt] = *(const bf16x8*)&Bs[cur][(wn * 32 + nt * 16 + l16) * 64 + slot];
#pragma unroll
      for (int mt = 0; mt < 4; mt++)
#pragma unroll
        for (int nt = 0; nt < 2; nt++)
          acc[mt][nt] = __builtin_amdgcn_mfma_f32_16x16x32_bf16(af[mt], bf_[nt], acc[mt][nt], 0, 0, 0);
    }
    asm volatile("" ::: "memory");
    __builtin_amdgcn_s_barrier();   // reads of buf[cur] done before it's restaged
  }
#undef STAGE
  // ---- epilogue: y = x + linv[m] * delta ----
  float li[4][4];
#pragma unroll
  for (int mt = 0; mt < 4; mt++)
#pragma unroll
    for (int r = 0; r < 4; r++)
      li[mt][r] = linv_g[(size_t)b * Nn + m0 + wm * 64 + mt * 16 + quad * 4 + r];
#pragma unroll
  for (int mt = 0; mt < 4; mt++)
#pragma unroll
    for (int nt = 0; nt < 2; nt++) {
      const int nn = n0 + wn * 32 + nt * 16 + l16;
#pragma unroll
      for (int r = 0; r < 4; r++) {
        const int m = m0 + wm * 64 + mt * 16 + quad * 4 + r;
        const size_t off = ((size_t)(b * Nn + m)) * Dd + nn;
        y[off] = x[off] + li[mt][r] * acc[mt][nt][r];
      }
    }
}

// ---- ln_k: in-place row-wise LayerNorm over d_out. 1 block (256 thr) per row ----
__global__ __launch_bounds__(256) void ln_k(float* __restrict__ y,
    const float* __restrict__ gamma, const float* __restrict__ beta) {
  __shared__ float rs[4], rq[4];
  const int row = blockIdx.x;
  const int t = threadIdx.x;
  float* p = y + (size_t)row * Dd;
  float4 v = ((const float4*)p)[t];
  float s = v.x + v.y + v.z + v.w;
  float q = v.x * v.x + v.y * v.y + v.z * v.z + v.w * v.w;
#pragma unroll
  for (int off = 32; off; off >>= 1) {
    s += __shfl_xor(s, off);
    q += __shfl_xor(q, off);
  }
  if ((t & 63) == 0) { rs[t >> 6] = s; rq[t >> 6] = q; }
  __syncthreads();
  float S = rs[0] + rs[1] + rs[2] + rs[3];
  float Q2 = rq[0] + rq[1] + rq[2] + rq[3];
  float mu = S * (1.f / Dd);
  float var = Q2 * (1.f / Dd) - mu * mu;
  float rstd = rsqrtf(var + LN_EPS);
  float4 g = ((const float4*)gamma)[t];
  float4 be = ((const float4*)beta)[t];
  v.x = (v.x - mu) * rstd * g.x + be.x;
  v.y = (v.y - mu) * rstd * g.y + be.y;
  v.z = (v.z - mu) * rstd * g.z + be.z;
  v.w = (v.w - mu) * rstd * g.w + be.w;
  ((float4*)p)[t] = v;
}

extern "C" void kernel_launch(void* const* d_in, const int* in_sizes, int n_in,
                              void* d_out, int out_size, void* d_ws, size_t ws_size,
                              hipStream_t stream) {
  const float* x     = (const float*)d_in[0];
  const float* mask  = (const float*)d_in[1];
  const float* U     = (const float*)d_in[2];
  const float* V     = (const float*)d_in[3];
  const float* gamma = (const float*)d_in[4];
  const float* beta  = (const float*)d_in[5];
  float* out = (float*)d_out;
  char* ws = (char*)d_ws;
  // workspace layout (51 MB total)
  u16*   xt   = (u16*)ws;                                        // 16 MB (B,D,N) bf16
  u16*   Qw   = (u16*)(ws + (size_t)(16 << 20));                 // 1 MB
  u16*   Kw   = (u16*)(ws + (size_t)(17 << 20));                 // 1 MB
  u16*   uvt  = (u16*)(ws + (size_t)(18 << 20));                 // 256 KB
  float* qsb  = (float*)(ws + (size_t)(18 << 20) + (256 << 10)); // 32 KB
  float* linv = (float*)(ws + (size_t)(18 << 20) + (288 << 10)); // 32 KB
  u16*   Pw   = (u16*)(ws + (size_t)(19 << 20));                 // 32 MB (B,N,N) bf16

  prep_fused   <<<4128, 256, 0, stream>>>(x, xt, U, V, mask, uvt, qsb);
  proj_qk      <<<(Bb * Nn) / 16, 256, 0, stream>>>(x, mask, uvt, Qw, Kw);
  score_softmax<<<Bb * (Nn / 16), 512, 0, stream>>>(Qw, Kw, qsb, Pw, linv);
  pv_gemm      <<<Bb * (Nn / 128) * (Dd / 128), 512, 0, stream>>>(Pw, xt, x, linv, out);
  ln_k         <<<Bb * Nn, 256, 0, stream>>>(out, gamma, beta);
}

// Round 8
// 188.575 us; speedup vs baseline: 1.0518x; 1.0518x over previous
//
#include <hip/hip_runtime.h>

#define Bb 4
#define Nn 2048
#define Dd 1024
#define Rr 64
#define LN_EPS 1e-5f

typedef unsigned short u16;
typedef short bf16x8 __attribute__((ext_vector_type(8)));   // 8 bf16 in 4 VGPRs
typedef float f32x4 __attribute__((ext_vector_type(4)));

__device__ __forceinline__ u16 f2bf(float f) {
  unsigned u = __float_as_uint(f);
  u += 0x7FFFu + ((u >> 16) & 1u);   // RNE
  return (u16)(u >> 16);
}

// async global->LDS, 16 B per lane. LDS dest is wave-uniform base + lane*16.
__device__ __forceinline__ void g2l16(u16* l, const u16* g) {
  __builtin_amdgcn_global_load_lds(
      (const __attribute__((address_space(1))) unsigned int*)g,
      (__attribute__((address_space(3))) unsigned int*)l, 16, 0, 0);
}

// ---- prep_fused: blocks 0..2047 = prep_x transpose; 2048..2079 = U/V
// transpose; 2080..4127 = qscale. (R7; same work as split kernels, -1 launch)
__global__ __launch_bounds__(256) void prep_fused(const float* __restrict__ x,
    u16* __restrict__ xt, const float* __restrict__ U,
    const float* __restrict__ V, const float* __restrict__ mask,
    u16* __restrict__ uvt, float* __restrict__ qs) {
  __shared__ float tile[64][65];
  const int bid = blockIdx.x;
  const int t = threadIdx.x;
  if (bid < 2048) {
    const int b = bid >> 9;
    const int d0 = ((bid >> 5) & 15) * 64;
    const int n0 = (bid & 31) * 64;
    const int c = t & 63, r4 = t >> 6;
#pragma unroll
    for (int rr = 0; rr < 16; rr++) {
      int row = rr * 4 + r4;
      tile[row][c] = x[(size_t)(b * Nn + n0 + row) * Dd + d0 + c];
    }
    __syncthreads();
    const int c2 = t & 31, r8 = t >> 5;
#pragma unroll
    for (int rr = 0; rr < 8; rr++) {
      int dd = rr * 8 + r8;
      unsigned lo = f2bf(tile[2 * c2][dd]);
      unsigned hi = f2bf(tile[2 * c2 + 1][dd]);
      *(unsigned*)&xt[(size_t)(b * Dd + d0 + dd) * Nn + n0 + 2 * c2] = lo | (hi << 16);
    }
  } else if (bid < 2080) {
    const int sub = bid - 2048;
    const int which = sub >> 4;
    const int d0 = (sub & 15) * 64;
    const float* src = which ? V : U;
    const int c = t & 63, r4 = t >> 6;
#pragma unroll
    for (int rr = 0; rr < 16; rr++) {
      int row = rr * 4 + r4;
      tile[row][c] = src[(size_t)(d0 + row) * Rr + c];
    }
    __syncthreads();
#pragma unroll
    for (int rr = 0; rr < 16; rr++) {
      int r = rr * 4 + r4;
      uvt[(size_t)(which * 64 + r) * Dd + d0 + c] = f2bf(tile[c][r]);
    }
  } else {
    const int row = (bid - 2080) * 4 + (t >> 6);
    const int lane = t & 63;
    float v = mask[(size_t)row * Rr + lane];
#pragma unroll
    for (int off = 32; off; off >>= 1) v += __shfl_xor(v, off);
    if (lane == 0) qs[row] = rsqrtf(fmaxf(v, 1.0f));
  }
}

// ---- proj_qk: Q = (x@U)*mask, K = (x@V)*mask, bf16 out.
// R8: reverted to 32 rows x 128 cols/block (grid 256) — R7's 16-row split
// regressed (halved operand reuse; these kernels are reuse-bound, not
// occupancy-bound).
__global__ __launch_bounds__(256) void proj_qk(const float* __restrict__ x,
    const float* __restrict__ mask, const u16* __restrict__ uvt,
    u16* __restrict__ Qo, u16* __restrict__ Ko) {
  const int t = threadIdx.x;
  const int w = t >> 6, l = t & 63, quad = l >> 4, l16 = l & 15;
  const int g0 = blockIdx.x * 32;
  f32x4 acc[2][2];
#pragma unroll
  for (int i = 0; i < 2; i++)
#pragma unroll
    for (int j = 0; j < 2; j++) acc[i][j] = (f32x4){0.f, 0.f, 0.f, 0.f};
  for (int k0 = 0; k0 < Dd; k0 += 32) {
    bf16x8 a[2];
#pragma unroll
    for (int mt = 0; mt < 2; mt++) {
      const float4* px = (const float4*)&x[(size_t)(g0 + mt * 16 + l16) * Dd + k0 + quad * 8];
      float4 x0 = px[0], x1 = px[1];
      bf16x8 av;
      av[0] = (short)f2bf(x0.x); av[1] = (short)f2bf(x0.y);
      av[2] = (short)f2bf(x0.z); av[3] = (short)f2bf(x0.w);
      av[4] = (short)f2bf(x1.x); av[5] = (short)f2bf(x1.y);
      av[6] = (short)f2bf(x1.z); av[7] = (short)f2bf(x1.w);
      a[mt] = av;
    }
    bf16x8 bfr[2];
#pragma unroll
    for (int i = 0; i < 2; i++) {
      int col = (w * 2 + i) * 16 + l16;
      bfr[i] = *(const bf16x8*)&uvt[(size_t)col * Dd + k0 + quad * 8];
    }
#pragma unroll
    for (int mt = 0; mt < 2; mt++)
#pragma unroll
      for (int i = 0; i < 2; i++)
        acc[mt][i] = __builtin_amdgcn_mfma_f32_16x16x32_bf16(a[mt], bfr[i], acc[mt][i], 0, 0, 0);
  }
#pragma unroll
  for (int mt = 0; mt < 2; mt++)
#pragma unroll
    for (int i = 0; i < 2; i++) {
      int col = (w * 2 + i) * 16 + l16;
      int r_ = col & 63;
#pragma unroll
      for (int r = 0; r < 4; r++) {
        int row = g0 + mt * 16 + quad * 4 + r;
        float v = acc[mt][i][r] * mask[(size_t)row * Rr + r_];
        u16 bv = f2bf(v);
        if (col < 64) Qo[(size_t)row * Rr + r_] = bv;
        else          Ko[(size_t)row * Rr + r_] = bv;
      }
    }
}

// ---- score_softmax: block = 32 q-rows x ALL 2048 keys, 8 waves (R5 geom).
// R8: Pw store path reworked. Was 128 scalar 2B global stores/lane (each
// wave-store = 4 rows x 32B fragments — the same pattern whose u32-pack fix
// in prep_x measured -3.6 us on half the bytes). Now: each wave bounces its
// 32x256 P-slice through LDS (disjoint per wave -> no barrier; same-wave
// RAW ordered by compiler lgkmcnt) and stores back as 16 b128 stores,
// each 8 rows x 128 B contiguous. Bit-identical P values.
__global__ __launch_bounds__(512, 2) void score_softmax(
    const u16* __restrict__ Qm, const u16* __restrict__ Km,
    const float* __restrict__ qs, u16* __restrict__ Pw,
    float* __restrict__ linv_g) {
  __shared__ float red[32][8];
  __shared__ float mfin[32];
  __shared__ __align__(16) u16 Ps[8][32][264];   // 135 KB; +264 pad vs 256
  const int t = threadIdx.x;
  const int w = t >> 6, l = t & 63, quad = l >> 4, l16 = l & 15;
  const int id = blockIdx.x;
  const int xcd = id & 7;
  const int b = xcd >> 1;
  const int q0 = (((id >> 3) << 1) | (xcd & 1)) * 32;
  bf16x8 qf[2][2];
#pragma unroll
  for (int mt = 0; mt < 2; mt++)
#pragma unroll
    for (int ks = 0; ks < 2; ks++)
      qf[mt][ks] = *(const bf16x8*)&Qm[(size_t)(b * Nn + q0 + mt * 16 + l16) * Rr + ks * 32 + quad * 8];
  f32x4 acc[2][16];
#pragma unroll
  for (int mt = 0; mt < 2; mt++)
#pragma unroll
    for (int nt = 0; nt < 16; nt++) acc[mt][nt] = (f32x4){0.f, 0.f, 0.f, 0.f};
#pragma unroll
  for (int nt = 0; nt < 16; nt++) {
#pragma unroll
    for (int ks = 0; ks < 2; ks++) {
      bf16x8 kf = *(const bf16x8*)&Km[(size_t)(b * Nn + w * 256 + nt * 16 + l16) * Rr + ks * 32 + quad * 8];
#pragma unroll
      for (int mt = 0; mt < 2; mt++)
        acc[mt][nt] = __builtin_amdgcn_mfma_f32_16x16x32_bf16(qf[mt][ks], kf, acc[mt][nt], 0, 0, 0);
    }
  }
  float sc[2][4];
#pragma unroll
  for (int mt = 0; mt < 2; mt++)
#pragma unroll
    for (int r = 0; r < 4; r++)
      sc[mt][r] = qs[(size_t)b * Nn + q0 + mt * 16 + quad * 4 + r];
#pragma unroll
  for (int mt = 0; mt < 2; mt++)
#pragma unroll
    for (int nt = 0; nt < 16; nt++)
#pragma unroll
      for (int r = 0; r < 4; r++) acc[mt][nt][r] *= sc[mt][r];
  float vmax[2][4];
#pragma unroll
  for (int mt = 0; mt < 2; mt++)
#pragma unroll
    for (int r = 0; r < 4; r++) {
      float m = -1e30f;
#pragma unroll
      for (int nt = 0; nt < 16; nt++) m = fmaxf(m, acc[mt][nt][r]);
#pragma unroll
      for (int off = 1; off < 16; off <<= 1) m = fmaxf(m, __shfl_xor(m, off));
      vmax[mt][r] = m;
    }
  if (l16 == 0) {
#pragma unroll
    for (int mt = 0; mt < 2; mt++)
#pragma unroll
      for (int r = 0; r < 4; r++) red[mt * 16 + quad * 4 + r][w] = vmax[mt][r];
  }
  __syncthreads();
  if (t < 32) {
    float m = -1e30f;
#pragma unroll
    for (int i = 0; i < 8; i++) m = fmaxf(m, red[t][i]);
    mfin[t] = m;
  }
  __syncthreads();
  float rowm[2][4], vsum[2][4];
#pragma unroll
  for (int mt = 0; mt < 2; mt++)
#pragma unroll
    for (int r = 0; r < 4; r++) {
      rowm[mt][r] = mfin[mt * 16 + quad * 4 + r];
      vsum[mt][r] = 0.f;
    }
#pragma unroll
  for (int mt = 0; mt < 2; mt++)
#pragma unroll
    for (int nt = 0; nt < 16; nt++)
#pragma unroll
      for (int r = 0; r < 4; r++) {
        float p = __expf(acc[mt][nt][r] - rowm[mt][r]);
        acc[mt][nt][r] = p;
        vsum[mt][r] += p;
      }
#pragma unroll
  for (int mt = 0; mt < 2; mt++)
#pragma unroll
    for (int r = 0; r < 4; r++) {
#pragma unroll
      for (int off = 1; off < 16; off <<= 1) vsum[mt][r] += __shfl_xor(vsum[mt][r], off);
    }
  __syncthreads();   // red[] reuse
  if (l16 == 0) {
#pragma unroll
    for (int mt = 0; mt < 2; mt++)
#pragma unroll
      for (int r = 0; r < 4; r++) red[mt * 16 + quad * 4 + r][w] = vsum[mt][r];
  }
  __syncthreads();
  if (t < 32) {
    float s = 0.f;
#pragma unroll
    for (int i = 0; i < 8; i++) s += red[t][i];
    linv_g[(size_t)b * Nn + q0 + t] = 1.f / s;
  }
  // ---- P -> LDS (per-wave slice, scalar b16 writes) ----
#pragma unroll
  for (int mt = 0; mt < 2; mt++)
#pragma unroll
    for (int nt = 0; nt < 16; nt++)
#pragma unroll
      for (int r = 0; r < 4; r++)
        Ps[w][mt * 16 + quad * 4 + r][nt * 16 + l16] = f2bf(acc[mt][nt][r]);
  // ---- LDS -> global, 16 x b128 coalesced stores (8 rows x 128 B each) ----
  const int rrow = l >> 3, rcol = (l & 7) * 8;
#pragma unroll
  for (int rr = 0; rr < 4; rr++)
#pragma unroll
    for (int cc = 0; cc < 4; cc++) {
      const int row = rr * 8 + rrow;
      const int col = cc * 64 + rcol;
      bf16x8 v = *(const bf16x8*)&Ps[w][row][col];
      *(bf16x8*)&Pw[(size_t)(b * Nn + q0 + row) * Nn + w * 256 + col] = v;
    }
}

// ---- pv_gemm: delta = P @ X. 128x128 tile, BK=64, 512 thr (8 waves 2Mx4N),
// double-buffered LDS + counted vmcnt — R5 exact (best measured 43.7-44.3 us;
// plateaued: 4w/8w, BK64/128, drain0/counted, 1/2-buf all within 44-46).
__global__ __launch_bounds__(512, 4) void pv_gemm(
    const u16* __restrict__ Pw, const u16* __restrict__ xt,
    const float* __restrict__ x, const float* __restrict__ linv_g,
    float* __restrict__ y) {
  __shared__ u16 As[2][128 * 64];   // [buf][row m][k-slot] swizzled, 16 KB ea
  __shared__ u16 Bs[2][128 * 64];   // [buf][col n(d)][k-slot] swizzled
  const int t = threadIdx.x;
  const int w = t >> 6, l = t & 63, quad = l >> 4, l16 = l & 15;
  const int id = blockIdx.x;
  const int xcd = id & 7;
  const int b = xcd >> 1;
  const int nh = xcd & 1;
  const int rest = id >> 3;             // 0..63
  const int m0 = (rest & 15) * 128;     // 16 m-tiles
  const int n0 = (nh * 4 + (rest >> 4)) * 128;  // 8 n-tiles
  const int lrow = l >> 3;              // 0..7
  const int srow = w * 8 + lrow;        // staging row 0..63 (+64 second round)
  const int skoff = ((l & 7) ^ lrow) * 8;  // swizzled global k-chunk
  const size_t gA = (size_t)(b * Nn + m0 + srow) * Nn + skoff;
  const size_t gB = (size_t)(b * Dd + n0 + srow) * Nn + skoff;
  const int wm = w >> 2, wn = w & 3;    // 2M x 4N wave grid
  const int sw = l16 & 7;
  f32x4 acc[4][2];
#pragma unroll
  for (int i = 0; i < 4; i++)
#pragma unroll
    for (int j = 0; j < 2; j++) acc[i][j] = (f32x4){0.f, 0.f, 0.f, 0.f};

#define STAGE(bf, k0)                                              \
  do {                                                             \
    g2l16(&As[bf][(w * 8) * 64],      &Pw[gA + (size_t)(k0)]);     \
    g2l16(&As[bf][(64 + w * 8) * 64], &Pw[gA + 64 * Nn + (size_t)(k0)]); \
    g2l16(&Bs[bf][(w * 8) * 64],      &xt[gB + (size_t)(k0)]);     \
    g2l16(&Bs[bf][(64 + w * 8) * 64], &xt[gB + 64 * Nn + (size_t)(k0)]); \
  } while (0)

  STAGE(0, 0);   // tile 0 in flight (4 outstanding/wave)
  for (int kt = 0; kt < Nn / 64; kt++) {
    const int cur = kt & 1;
    if (kt + 1 < Nn / 64) {
      STAGE(cur ^ 1, (kt + 1) * 64);              // up to 8 outstanding
      asm volatile("s_waitcnt vmcnt(4)" ::: "memory");  // tile kt done; kt+1 flies
    } else {
      asm volatile("s_waitcnt vmcnt(0)" ::: "memory");  // last tile: drain it
    }
    __builtin_amdgcn_s_barrier();                 // all waves' tile-kt data in LDS
    asm volatile("" ::: "memory");
#pragma unroll
    for (int ks = 0; ks < 2; ks++) {
      const int slot = ((ks * 4 + quad) ^ sw) * 8;
      bf16x8 af[4], bf_[2];
#pragma unroll
      for (int mt = 0; mt < 4; mt++)
        af[mt] = *(const bf16x8*)&As[cur][(wm * 64 + mt * 16 + l16) * 64 + slot];
#pragma unroll
      for (int nt = 0; nt < 2; nt++)
        bf_[nt] = *(const bf16x8*)&Bs[cur][(wn * 32 + nt * 16 + l16) * 64 + slot];
#pragma unroll
      for (int mt = 0; mt < 4; mt++)
#pragma unroll
        for (int nt = 0; nt < 2; nt++)
          acc[mt][nt] = __builtin_amdgcn_mfma_f32_16x16x32_bf16(af[mt], bf_[nt], acc[mt][nt], 0, 0, 0);
    }
    asm volatile("" ::: "memory");
    __builtin_amdgcn_s_barrier();   // reads of buf[cur] done before it's restaged
  }
#undef STAGE
  // ---- epilogue: y = x + linv[m] * delta ----
  float li[4][4];
#pragma unroll
  for (int mt = 0; mt < 4; mt++)
#pragma unroll
    for (int r = 0; r < 4; r++)
      li[mt][r] = linv_g[(size_t)b * Nn + m0 + wm * 64 + mt * 16 + quad * 4 + r];
#pragma unroll
  for (int mt = 0; mt < 4; mt++)
#pragma unroll
    for (int nt = 0; nt < 2; nt++) {
      const int nn = n0 + wn * 32 + nt * 16 + l16;
#pragma unroll
      for (int r = 0; r < 4; r++) {
        const int m = m0 + wm * 64 + mt * 16 + quad * 4 + r;
        const size_t off = ((size_t)(b * Nn + m)) * Dd + nn;
        y[off] = x[off] + li[mt][r] * acc[mt][nt][r];
      }
    }
}

// ---- ln_k: in-place row-wise LayerNorm over d_out. 1 block (256 thr) per row ----
__global__ __launch_bounds__(256) void ln_k(float* __restrict__ y,
    const float* __restrict__ gamma, const float* __restrict__ beta) {
  __shared__ float rs[4], rq[4];
  const int row = blockIdx.x;
  const int t = threadIdx.x;
  float* p = y + (size_t)row * Dd;
  float4 v = ((const float4*)p)[t];
  float s = v.x + v.y + v.z + v.w;
  float q = v.x * v.x + v.y * v.y + v.z * v.z + v.w * v.w;
#pragma unroll
  for (int off = 32; off; off >>= 1) {
    s += __shfl_xor(s, off);
    q += __shfl_xor(q, off);
  }
  if ((t & 63) == 0) { rs[t >> 6] = s; rq[t >> 6] = q; }
  __syncthreads();
  float S = rs[0] + rs[1] + rs[2] + rs[3];
  float Q2 = rq[0] + rq[1] + rq[2] + rq[3];
  float mu = S * (1.f / Dd);
  float var = Q2 * (1.f / Dd) - mu * mu;
  float rstd = rsqrtf(var + LN_EPS);
  float4 g = ((const float4*)gamma)[t];
  float4 be = ((const float4*)beta)[t];
  v.x = (v.x - mu) * rstd * g.x + be.x;
  v.y = (v.y - mu) * rstd * g.y + be.y;
  v.z = (v.z - mu) * rstd * g.z + be.z;
  v.w = (v.w - mu) * rstd * g.w + be.w;
  ((float4*)p)[t] = v;
}

extern "C" void kernel_launch(void* const* d_in, const int* in_sizes, int n_in,
                              void* d_out, int out_size, void* d_ws, size_t ws_size,
                              hipStream_t stream) {
  const float* x     = (const float*)d_in[0];
  const float* mask  = (const float*)d_in[1];
  const float* U     = (const float*)d_in[2];
  const float* V     = (const float*)d_in[3];
  const float* gamma = (const float*)d_in[4];
  const float* beta  = (const float*)d_in[5];
  float* out = (float*)d_out;
  char* ws = (char*)d_ws;
  // workspace layout (51 MB total)
  u16*   xt   = (u16*)ws;                                        // 16 MB (B,D,N) bf16
  u16*   Qw   = (u16*)(ws + (size_t)(16 << 20));                 // 1 MB
  u16*   Kw   = (u16*)(ws + (size_t)(17 << 20));                 // 1 MB
  u16*   uvt  = (u16*)(ws + (size_t)(18 << 20));                 // 256 KB
  float* qsb  = (float*)(ws + (size_t)(18 << 20) + (256 << 10)); // 32 KB
  float* linv = (float*)(ws + (size_t)(18 << 20) + (288 << 10)); // 32 KB
  u16*   Pw   = (u16*)(ws + (size_t)(19 << 20));                 // 32 MB (B,N,N) bf16

  prep_fused   <<<4128, 256, 0, stream>>>(x, xt, U, V, mask, uvt, qsb);
  proj_qk      <<<(Bb * Nn) / 32, 256, 0, stream>>>(x, mask, uvt, Qw, Kw);
  score_softmax<<<Bb * (Nn / 32), 512, 0, stream>>>(Qw, Kw, qsb, Pw, linv);
  pv_gemm      <<<Bb * (Nn / 128) * (Dd / 128), 512, 0, stream>>>(Pw, xt, x, linv, out);
  ln_k         <<<Bb * Nn, 256, 0, stream>>>(out, gamma, beta);
}

// Round 9
// 185.413 us; speedup vs baseline: 1.0697x; 1.0171x over previous
//
#include <hip/hip_runtime.h>

#define Bb 4
#define Nn 2048
#define Dd 1024
#define Rr 64
#define LN_EPS 1e-5f

typedef unsigned short u16;
typedef short bf16x8 __attribute__((ext_vector_type(8)));   // 8 bf16 in 4 VGPRs
typedef float f32x4 __attribute__((ext_vector_type(4)));

__device__ __forceinline__ u16 f2bf(float f) {
  unsigned u = __float_as_uint(f);
  u += 0x7FFFu + ((u >> 16) & 1u);   // RNE
  return (u16)(u >> 16);
}

// async global->LDS, 16 B per lane. LDS dest is wave-uniform base + lane*16.
__device__ __forceinline__ void g2l16(u16* l, const u16* g) {
  __builtin_amdgcn_global_load_lds(
      (const __attribute__((address_space(1))) unsigned int*)g,
      (__attribute__((address_space(3))) unsigned int*)l, 16, 0, 0);
}

// ---- prep_fused: blocks 0..2047 = prep_x transpose (+R9: row-major bf16
// copy xb, value already in-register -> 128B-contiguous u16 stores);
// 2048..2079 = U/V transpose; 2080..4127 = qscale.
__global__ __launch_bounds__(256) void prep_fused(const float* __restrict__ x,
    u16* __restrict__ xt, u16* __restrict__ xb, const float* __restrict__ U,
    const float* __restrict__ V, const float* __restrict__ mask,
    u16* __restrict__ uvt, float* __restrict__ qs) {
  __shared__ float tile[64][65];
  const int bid = blockIdx.x;
  const int t = threadIdx.x;
  if (bid < 2048) {
    const int b = bid >> 9;
    const int d0 = ((bid >> 5) & 15) * 64;
    const int n0 = (bid & 31) * 64;
    const int c = t & 63, r4 = t >> 6;
#pragma unroll
    for (int rr = 0; rr < 16; rr++) {
      int row = rr * 4 + r4;
      const size_t off = (size_t)(b * Nn + n0 + row) * Dd + d0 + c;
      float v = x[off];
      tile[row][c] = v;
      xb[off] = f2bf(v);          // R9: bf16 row-major copy for proj_qk
    }
    __syncthreads();
    const int c2 = t & 31, r8 = t >> 5;
#pragma unroll
    for (int rr = 0; rr < 8; rr++) {
      int dd = rr * 8 + r8;
      unsigned lo = f2bf(tile[2 * c2][dd]);
      unsigned hi = f2bf(tile[2 * c2 + 1][dd]);
      *(unsigned*)&xt[(size_t)(b * Dd + d0 + dd) * Nn + n0 + 2 * c2] = lo | (hi << 16);
    }
  } else if (bid < 2080) {
    const int sub = bid - 2048;
    const int which = sub >> 4;
    const int d0 = (sub & 15) * 64;
    const float* src = which ? V : U;
    const int c = t & 63, r4 = t >> 6;
#pragma unroll
    for (int rr = 0; rr < 16; rr++) {
      int row = rr * 4 + r4;
      tile[row][c] = src[(size_t)(d0 + row) * Rr + c];
    }
    __syncthreads();
#pragma unroll
    for (int rr = 0; rr < 16; rr++) {
      int r = rr * 4 + r4;
      uvt[(size_t)(which * 64 + r) * Dd + d0 + c] = f2bf(tile[c][r]);
    }
  } else {
    const int row = (bid - 2080) * 4 + (t >> 6);
    const int lane = t & 63;
    float v = mask[(size_t)row * Rr + lane];
#pragma unroll
    for (int off = 32; off; off >>= 1) v += __shfl_xor(v, off);
    if (lane == 0) qs[row] = rsqrtf(fmaxf(v, 1.0f));
  }
}

// ---- proj_qk: Q = (x@U)*mask, K = (x@V)*mask, bf16 out.
// 32 rows x 128 cols/block (grid 256). R9: A-operand from xb (bf16
// row-major, pre-converted in prep_fused): one bf16x8 load replaces
// 2x float4 + 16 f2bf/pack per mt — half the input bytes, ~zero
// conversion VALU in the 1-wave/SIMD critical loop. Bit-identical Q/K.
__global__ __launch_bounds__(256) void proj_qk(const u16* __restrict__ xb,
    const float* __restrict__ mask, const u16* __restrict__ uvt,
    u16* __restrict__ Qo, u16* __restrict__ Ko) {
  const int t = threadIdx.x;
  const int w = t >> 6, l = t & 63, quad = l >> 4, l16 = l & 15;
  const int g0 = blockIdx.x * 32;
  f32x4 acc[2][2];
#pragma unroll
  for (int i = 0; i < 2; i++)
#pragma unroll
    for (int j = 0; j < 2; j++) acc[i][j] = (f32x4){0.f, 0.f, 0.f, 0.f};
  for (int k0 = 0; k0 < Dd; k0 += 32) {
    bf16x8 a[2];
#pragma unroll
    for (int mt = 0; mt < 2; mt++)
      a[mt] = *(const bf16x8*)&xb[(size_t)(g0 + mt * 16 + l16) * Dd + k0 + quad * 8];
    bf16x8 bfr[2];
#pragma unroll
    for (int i = 0; i < 2; i++) {
      int col = (w * 2 + i) * 16 + l16;
      bfr[i] = *(const bf16x8*)&uvt[(size_t)col * Dd + k0 + quad * 8];
    }
#pragma unroll
    for (int mt = 0; mt < 2; mt++)
#pragma unroll
      for (int i = 0; i < 2; i++)
        acc[mt][i] = __builtin_amdgcn_mfma_f32_16x16x32_bf16(a[mt], bfr[i], acc[mt][i], 0, 0, 0);
  }
#pragma unroll
  for (int mt = 0; mt < 2; mt++)
#pragma unroll
    for (int i = 0; i < 2; i++) {
      int col = (w * 2 + i) * 16 + l16;
      int r_ = col & 63;
#pragma unroll
      for (int r = 0; r < 4; r++) {
        int row = g0 + mt * 16 + quad * 4 + r;
        float v = acc[mt][i][r] * mask[(size_t)row * Rr + r_];
        u16 bv = f2bf(v);
        if (col < 64) Qo[(size_t)row * Rr + r_] = bv;
        else          Ko[(size_t)row * Rr + r_] = bv;
      }
    }
}

// ---- score_softmax: block = 32 q-rows x ALL 2048 keys, 8 waves (R5 geom).
// R8 store path kept (LDS bounce -> b128 coalesced stores; bit-identical).
__global__ __launch_bounds__(512, 2) void score_softmax(
    const u16* __restrict__ Qm, const u16* __restrict__ Km,
    const float* __restrict__ qs, u16* __restrict__ Pw,
    float* __restrict__ linv_g) {
  __shared__ float red[32][8];
  __shared__ float mfin[32];
  __shared__ __align__(16) u16 Ps[8][32][264];   // 135 KB; +264 pad vs 256
  const int t = threadIdx.x;
  const int w = t >> 6, l = t & 63, quad = l >> 4, l16 = l & 15;
  const int id = blockIdx.x;
  const int xcd = id & 7;
  const int b = xcd >> 1;
  const int q0 = (((id >> 3) << 1) | (xcd & 1)) * 32;
  bf16x8 qf[2][2];
#pragma unroll
  for (int mt = 0; mt < 2; mt++)
#pragma unroll
    for (int ks = 0; ks < 2; ks++)
      qf[mt][ks] = *(const bf16x8*)&Qm[(size_t)(b * Nn + q0 + mt * 16 + l16) * Rr + ks * 32 + quad * 8];
  f32x4 acc[2][16];
#pragma unroll
  for (int mt = 0; mt < 2; mt++)
#pragma unroll
    for (int nt = 0; nt < 16; nt++) acc[mt][nt] = (f32x4){0.f, 0.f, 0.f, 0.f};
#pragma unroll
  for (int nt = 0; nt < 16; nt++) {
#pragma unroll
    for (int ks = 0; ks < 2; ks++) {
      bf16x8 kf = *(const bf16x8*)&Km[(size_t)(b * Nn + w * 256 + nt * 16 + l16) * Rr + ks * 32 + quad * 8];
#pragma unroll
      for (int mt = 0; mt < 2; mt++)
        acc[mt][nt] = __builtin_amdgcn_mfma_f32_16x16x32_bf16(qf[mt][ks], kf, acc[mt][nt], 0, 0, 0);
    }
  }
  float sc[2][4];
#pragma unroll
  for (int mt = 0; mt < 2; mt++)
#pragma unroll
    for (int r = 0; r < 4; r++)
      sc[mt][r] = qs[(size_t)b * Nn + q0 + mt * 16 + quad * 4 + r];
#pragma unroll
  for (int mt = 0; mt < 2; mt++)
#pragma unroll
    for (int nt = 0; nt < 16; nt++)
#pragma unroll
      for (int r = 0; r < 4; r++) acc[mt][nt][r] *= sc[mt][r];
  float vmax[2][4];
#pragma unroll
  for (int mt = 0; mt < 2; mt++)
#pragma unroll
    for (int r = 0; r < 4; r++) {
      float m = -1e30f;
#pragma unroll
      for (int nt = 0; nt < 16; nt++) m = fmaxf(m, acc[mt][nt][r]);
#pragma unroll
      for (int off = 1; off < 16; off <<= 1) m = fmaxf(m, __shfl_xor(m, off));
      vmax[mt][r] = m;
    }
  if (l16 == 0) {
#pragma unroll
    for (int mt = 0; mt < 2; mt++)
#pragma unroll
      for (int r = 0; r < 4; r++) red[mt * 16 + quad * 4 + r][w] = vmax[mt][r];
  }
  __syncthreads();
  if (t < 32) {
    float m = -1e30f;
#pragma unroll
    for (int i = 0; i < 8; i++) m = fmaxf(m, red[t][i]);
    mfin[t] = m;
  }
  __syncthreads();
  float rowm[2][4], vsum[2][4];
#pragma unroll
  for (int mt = 0; mt < 2; mt++)
#pragma unroll
    for (int r = 0; r < 4; r++) {
      rowm[mt][r] = mfin[mt * 16 + quad * 4 + r];
      vsum[mt][r] = 0.f;
    }
#pragma unroll
  for (int mt = 0; mt < 2; mt++)
#pragma unroll
    for (int nt = 0; nt < 16; nt++)
#pragma unroll
      for (int r = 0; r < 4; r++) {
        float p = __expf(acc[mt][nt][r] - rowm[mt][r]);
        acc[mt][nt][r] = p;
        vsum[mt][r] += p;
      }
#pragma unroll
  for (int mt = 0; mt < 2; mt++)
#pragma unroll
    for (int r = 0; r < 4; r++) {
#pragma unroll
      for (int off = 1; off < 16; off <<= 1) vsum[mt][r] += __shfl_xor(vsum[mt][r], off);
    }
  __syncthreads();   // red[] reuse
  if (l16 == 0) {
#pragma unroll
    for (int mt = 0; mt < 2; mt++)
#pragma unroll
      for (int r = 0; r < 4; r++) red[mt * 16 + quad * 4 + r][w] = vsum[mt][r];
  }
  __syncthreads();
  if (t < 32) {
    float s = 0.f;
#pragma unroll
    for (int i = 0; i < 8; i++) s += red[t][i];
    linv_g[(size_t)b * Nn + q0 + t] = 1.f / s;
  }
  // ---- P -> LDS (per-wave slice, scalar b16 writes) ----
#pragma unroll
  for (int mt = 0; mt < 2; mt++)
#pragma unroll
    for (int nt = 0; nt < 16; nt++)
#pragma unroll
      for (int r = 0; r < 4; r++)
        Ps[w][mt * 16 + quad * 4 + r][nt * 16 + l16] = f2bf(acc[mt][nt][r]);
  // ---- LDS -> global, 16 x b128 coalesced stores (8 rows x 128 B each) ----
  const int rrow = l >> 3, rcol = (l & 7) * 8;
#pragma unroll
  for (int rr = 0; rr < 4; rr++)
#pragma unroll
    for (int cc = 0; cc < 4; cc++) {
      const int row = rr * 8 + rrow;
      const int col = cc * 64 + rcol;
      bf16x8 v = *(const bf16x8*)&Ps[w][row][col];
      *(bf16x8*)&Pw[(size_t)(b * Nn + q0 + row) * Nn + w * 256 + col] = v;
    }
}

// ---- pv_gemm: delta = P @ X. 128x128 tile, BK=64, 512 thr (8 waves 2Mx4N),
// double-buffered LDS + counted vmcnt — R5 exact (best measured 43.7-45.5;
// plateaued across 4w/8w, BK64/128, drain0/counted, 1/2-buf).
__global__ __launch_bounds__(512, 4) void pv_gemm(
    const u16* __restrict__ Pw, const u16* __restrict__ xt,
    const float* __restrict__ x, const float* __restrict__ linv_g,
    float* __restrict__ y) {
  __shared__ u16 As[2][128 * 64];   // [buf][row m][k-slot] swizzled, 16 KB ea
  __shared__ u16 Bs[2][128 * 64];   // [buf][col n(d)][k-slot] swizzled
  const int t = threadIdx.x;
  const int w = t >> 6, l = t & 63, quad = l >> 4, l16 = l & 15;
  const int id = blockIdx.x;
  const int xcd = id & 7;
  const int b = xcd >> 1;
  const int nh = xcd & 1;
  const int rest = id >> 3;             // 0..63
  const int m0 = (rest & 15) * 128;     // 16 m-tiles
  const int n0 = (nh * 4 + (rest >> 4)) * 128;  // 8 n-tiles
  const int lrow = l >> 3;              // 0..7
  const int srow = w * 8 + lrow;        // staging row 0..63 (+64 second round)
  const int skoff = ((l & 7) ^ lrow) * 8;  // swizzled global k-chunk
  const size_t gA = (size_t)(b * Nn + m0 + srow) * Nn + skoff;
  const size_t gB = (size_t)(b * Dd + n0 + srow) * Nn + skoff;
  const int wm = w >> 2, wn = w & 3;    // 2M x 4N wave grid
  const int sw = l16 & 7;
  f32x4 acc[4][2];
#pragma unroll
  for (int i = 0; i < 4; i++)
#pragma unroll
    for (int j = 0; j < 2; j++) acc[i][j] = (f32x4){0.f, 0.f, 0.f, 0.f};

#define STAGE(bf, k0)                                              \
  do {                                                             \
    g2l16(&As[bf][(w * 8) * 64],      &Pw[gA + (size_t)(k0)]);     \
    g2l16(&As[bf][(64 + w * 8) * 64], &Pw[gA + 64 * Nn + (size_t)(k0)]); \
    g2l16(&Bs[bf][(w * 8) * 64],      &xt[gB + (size_t)(k0)]);     \
    g2l16(&Bs[bf][(64 + w * 8) * 64], &xt[gB + 64 * Nn + (size_t)(k0)]); \
  } while (0)

  STAGE(0, 0);   // tile 0 in flight (4 outstanding/wave)
  for (int kt = 0; kt < Nn / 64; kt++) {
    const int cur = kt & 1;
    if (kt + 1 < Nn / 64) {
      STAGE(cur ^ 1, (kt + 1) * 64);              // up to 8 outstanding
      asm volatile("s_waitcnt vmcnt(4)" ::: "memory");  // tile kt done; kt+1 flies
    } else {
      asm volatile("s_waitcnt vmcnt(0)" ::: "memory");  // last tile: drain it
    }
    __builtin_amdgcn_s_barrier();                 // all waves' tile-kt data in LDS
    asm volatile("" ::: "memory");
#pragma unroll
    for (int ks = 0; ks < 2; ks++) {
      const int slot = ((ks * 4 + quad) ^ sw) * 8;
      bf16x8 af[4], bf_[2];
#pragma unroll
      for (int mt = 0; mt < 4; mt++)
        af[mt] = *(const bf16x8*)&As[cur][(wm * 64 + mt * 16 + l16) * 64 + slot];
#pragma unroll
      for (int nt = 0; nt < 2; nt++)
        bf_[nt] = *(const bf16x8*)&Bs[cur][(wn * 32 + nt * 16 + l16) * 64 + slot];
#pragma unroll
      for (int mt = 0; mt < 4; mt++)
#pragma unroll
        for (int nt = 0; nt < 2; nt++)
          acc[mt][nt] = __builtin_amdgcn_mfma_f32_16x16x32_bf16(af[mt], bf_[nt], acc[mt][nt], 0, 0, 0);
    }
    asm volatile("" ::: "memory");
    __builtin_amdgcn_s_barrier();   // reads of buf[cur] done before it's restaged
  }
#undef STAGE
  // ---- epilogue: y = x + linv[m] * delta ----
  float li[4][4];
#pragma unroll
  for (int mt = 0; mt < 4; mt++)
#pragma unroll
    for (int r = 0; r < 4; r++)
      li[mt][r] = linv_g[(size_t)b * Nn + m0 + wm * 64 + mt * 16 + quad * 4 + r];
#pragma unroll
  for (int mt = 0; mt < 4; mt++)
#pragma unroll
    for (int nt = 0; nt < 2; nt++) {
      const int nn = n0 + wn * 32 + nt * 16 + l16;
#pragma unroll
      for (int r = 0; r < 4; r++) {
        const int m = m0 + wm * 64 + mt * 16 + quad * 4 + r;
        const size_t off = ((size_t)(b * Nn + m)) * Dd + nn;
        y[off] = x[off] + li[mt][r] * acc[mt][nt][r];
      }
    }
}

// ---- ln_k: in-place row-wise LayerNorm over d_out. 1 block (256 thr) per row ----
__global__ __launch_bounds__(256) void ln_k(float* __restrict__ y,
    const float* __restrict__ gamma, const float* __restrict__ beta) {
  __shared__ float rs[4], rq[4];
  const int row = blockIdx.x;
  const int t = threadIdx.x;
  float* p = y + (size_t)row * Dd;
  float4 v = ((const float4*)p)[t];
  float s = v.x + v.y + v.z + v.w;
  float q = v.x * v.x + v.y * v.y + v.z * v.z + v.w * v.w;
#pragma unroll
  for (int off = 32; off; off >>= 1) {
    s += __shfl_xor(s, off);
    q += __shfl_xor(q, off);
  }
  if ((t & 63) == 0) { rs[t >> 6] = s; rq[t >> 6] = q; }
  __syncthreads();
  float S = rs[0] + rs[1] + rs[2] + rs[3];
  float Q2 = rq[0] + rq[1] + rq[2] + rq[3];
  float mu = S * (1.f / Dd);
  float var = Q2 * (1.f / Dd) - mu * mu;
  float rstd = rsqrtf(var + LN_EPS);
  float4 g = ((const float4*)gamma)[t];
  float4 be = ((const float4*)beta)[t];
  v.x = (v.x - mu) * rstd * g.x + be.x;
  v.y = (v.y - mu) * rstd * g.y + be.y;
  v.z = (v.z - mu) * rstd * g.z + be.z;
  v.w = (v.w - mu) * rstd * g.w + be.w;
  ((float4*)p)[t] = v;
}

extern "C" void kernel_launch(void* const* d_in, const int* in_sizes, int n_in,
                              void* d_out, int out_size, void* d_ws, size_t ws_size,
                              hipStream_t stream) {
  const float* x     = (const float*)d_in[0];
  const float* mask  = (const float*)d_in[1];
  const float* U     = (const float*)d_in[2];
  const float* V     = (const float*)d_in[3];
  const float* gamma = (const float*)d_in[4];
  const float* beta  = (const float*)d_in[5];
  float* out = (float*)d_out;
  char* ws = (char*)d_ws;
  // workspace layout (51 MB total)
  u16*   xt   = (u16*)ws;                                        // 16 MB (B,D,N) bf16
  u16*   Qw   = (u16*)(ws + (size_t)(16 << 20));                 // 1 MB
  u16*   Kw   = (u16*)(ws + (size_t)(17 << 20));                 // 1 MB
  u16*   uvt  = (u16*)(ws + (size_t)(18 << 20));                 // 256 KB
  float* qsb  = (float*)(ws + (size_t)(18 << 20) + (256 << 10)); // 32 KB
  float* linv = (float*)(ws + (size_t)(18 << 20) + (288 << 10)); // 32 KB
  u16*   Pw   = (u16*)(ws + (size_t)(19 << 20));                 // 32 MB (B,N,N) bf16
  // xb: bf16 row-major x for proj_qk. Aliases Pw's first 16 MB — proj reads
  // xb strictly before score writes Pw (stream-serialized), so no extra ws.
  u16*   xb   = Pw;

  prep_fused   <<<4128, 256, 0, stream>>>(x, xt, xb, U, V, mask, uvt, qsb);
  proj_qk      <<<(Bb * Nn) / 32, 256, 0, stream>>>(xb, mask, uvt, Qw, Kw);
  score_softmax<<<Bb * (Nn / 32), 512, 0, stream>>>(Qw, Kw, qsb, Pw, linv);
  pv_gemm      <<<Bb * (Nn / 128) * (Dd / 128), 512, 0, stream>>>(Pw, xt, x, linv, out);
  ln_k         <<<Bb * Nn, 256, 0, stream>>>(out, gamma, beta);
}